// Round 13
// baseline (876.870 us; speedup 1.0000x reference)
//
#include <hip/hip_runtime.h>
#include <stdint.h>
#include <math.h>

#define VV 128000
#define DD 2048
#define BB 32
#define SS 8
#define NCAND 4096
#define KSPLIT 8
#define KSLICE 256           // k per split
#define WS_NEED ((size_t)KSPLIT * BB * VV * 4)

// jax_threefry_partitionable 32-bit stream: counter=(0,flat), bits = o0 ^ o1.  (verified R4+)

#define GLDS(src, dst) __builtin_amdgcn_global_load_lds( \
    (const __attribute__((address_space(1))) void*)(src), \
    (__attribute__((address_space(3))) void*)(dst), 16, 0, 0)
#define CBAR() asm volatile("" ::: "memory")

// ---------------- threefry2x32 core (key = (0, 42) from jax.random.key(42)) ----------------
__device__ __forceinline__ uint32_t rotl32(uint32_t x, uint32_t r) {
    return (x << r) | (x >> (32u - r));
}

__device__ __forceinline__ void threefry2x32(uint32_t c0, uint32_t c1,
                                             uint32_t& o0, uint32_t& o1) {
    const uint32_t k0 = 0u, k1 = 42u;
    const uint32_t k2 = 0x1BD11BDAu ^ k0 ^ k1;
    uint32_t x0 = c0 + k0;
    uint32_t x1 = c1 + k1;
    #define TF_ROUND(r) { x0 += x1; x1 = rotl32(x1, r); x1 ^= x0; }
    TF_ROUND(13) TF_ROUND(15) TF_ROUND(26) TF_ROUND(6)
    x0 += k1; x1 += k2 + 1u;
    TF_ROUND(17) TF_ROUND(29) TF_ROUND(16) TF_ROUND(24)
    x0 += k2; x1 += k0 + 2u;
    TF_ROUND(13) TF_ROUND(15) TF_ROUND(26) TF_ROUND(6)
    x0 += k0; x1 += k1 + 3u;
    TF_ROUND(17) TF_ROUND(29) TF_ROUND(16) TF_ROUND(24)
    x0 += k1; x1 += k2 + 4u;
    TF_ROUND(13) TF_ROUND(15) TF_ROUND(26) TF_ROUND(6)
    x0 += k2; x1 += k0 + 5u;
    #undef TF_ROUND
    o0 = x0; o1 = x1;
}

__device__ float gumbel_at(uint32_t flat) {
    uint32_t o0, o1;
    threefry2x32(0u, flat, o0, o1);
    uint32_t bits = o0 ^ o1;
    uint32_t fb = (bits >> 9) | 0x3F800000u;
    float f = __uint_as_float(fb) - 1.0f;
    const float TINY = 1.17549435e-38f;
    float u = (f > 0.0f) ? f : TINY;
    return -logf(-logf(u));
}

__device__ __forceinline__ uint32_t enc_f32(float f) {
    uint32_t u = __float_as_uint(f);
    return u ^ (0x80000000u | (uint32_t)(((int32_t)u) >> 31));
}

// ---------------- K1a: partial GEMV over one K-slice ----------------
// grid (VV/8, KSPLIT) x 512 thr (8 waves). Block: 8 v-rows x 32 batches x 256 k.
// Wave w = row vbase+w. Lane: kl=lane&15 (k float4 slot), bl=lane>>4 (batch octet).
// h-slice staged once (32 KB LDS, 4 GLDS/thread, ONE barrier), then barrier-free
// compute: 4 chunks x {8 ds_read_b128 (2-way bank = free) + 32 FMAs}.
// acc[8] -> shuffle-reduce over kl -> partial to ws[ky][b][v].
// Small blocks + no in-loop sync -> ~24-32 independent waves/CU covering HBM latency.
__global__ __launch_bounds__(512, 6) void gemv_part(
    const float* __restrict__ emb, const float* __restrict__ hidden,
    const int* __restrict__ outpos, float* __restrict__ ws)
{
    __shared__ float h[BB][KSLICE];    // 32 KB

    const int tid  = threadIdx.x;
    const int w    = tid >> 6;
    const int lane = tid & 63;
    const int kl   = lane & 15;
    const int bl   = lane >> 4;
    const int ky   = blockIdx.y;
    const int v    = blockIdx.x * 8 + w;
    const int pos  = outpos[0];

    const float* hbase = hidden + (size_t)pos * DD + ky * KSLICE;

    // stage h-slice: round i, wave w -> row i*8+w (64 lanes x 16B = one 256-float row)
    #pragma unroll
    for (int i = 0; i < 4; ++i) {
        const int r = i * 8 + w;
        GLDS(hbase + (size_t)r * (SS * DD) + (lane << 2), &h[r][0]);
    }
    CBAR();
    // e: all 4 chunks prefetched up-front (stay in flight across stage wait)
    const float* er = emb + (size_t)v * DD + ky * KSLICE + (kl << 2);
    float4 e0 = *reinterpret_cast<const float4*>(er);
    float4 e1 = *reinterpret_cast<const float4*>(er + 64);
    float4 e2 = *reinterpret_cast<const float4*>(er + 128);
    float4 e3 = *reinterpret_cast<const float4*>(er + 192);
    CBAR();
    asm volatile("s_waitcnt vmcnt(4)" ::: "memory");   // 4 GLDS retired (e still flying)
    __builtin_amdgcn_s_barrier();
    CBAR();

    float acc[8];
    #pragma unroll
    for (int j = 0; j < 8; ++j) acc[j] = 0.0f;

    const char* hb = (const char*)&h[0][0];
    const int base = bl * 8 * 1024 + kl * 16;   // batch bl*8, this kl slot

    #define HALFP(C, E, J0) { \
        const float4 h0 = *reinterpret_cast<const float4*>(hb + base + (J0 + 0) * 1024 + (C) * 256); \
        const float4 h1 = *reinterpret_cast<const float4*>(hb + base + (J0 + 1) * 1024 + (C) * 256); \
        const float4 h2 = *reinterpret_cast<const float4*>(hb + base + (J0 + 2) * 1024 + (C) * 256); \
        const float4 h3 = *reinterpret_cast<const float4*>(hb + base + (J0 + 3) * 1024 + (C) * 256); \
        acc[J0 + 0] += E.x * h0.x; acc[J0 + 0] += E.y * h0.y; \
        acc[J0 + 0] += E.z * h0.z; acc[J0 + 0] += E.w * h0.w; \
        acc[J0 + 1] += E.x * h1.x; acc[J0 + 1] += E.y * h1.y; \
        acc[J0 + 1] += E.z * h1.z; acc[J0 + 1] += E.w * h1.w; \
        acc[J0 + 2] += E.x * h2.x; acc[J0 + 2] += E.y * h2.y; \
        acc[J0 + 2] += E.z * h2.z; acc[J0 + 2] += E.w * h2.w; \
        acc[J0 + 3] += E.x * h3.x; acc[J0 + 3] += E.y * h3.y; \
        acc[J0 + 3] += E.z * h3.z; acc[J0 + 3] += E.w * h3.w; }

    HALFP(0, e0, 0) HALFP(0, e0, 4)
    HALFP(1, e1, 0) HALFP(1, e1, 4)
    HALFP(2, e2, 0) HALFP(2, e2, 4)
    HALFP(3, e3, 0) HALFP(3, e3, 4)
    #undef HALFP

    // reduce over the 16 kl lanes (bl groups hold distinct batches)
    #pragma unroll
    for (int j = 0; j < 8; ++j) {
        float a = acc[j];
        a += __shfl_xor(a, 1, 64);
        a += __shfl_xor(a, 2, 64);
        a += __shfl_xor(a, 4, 64);
        a += __shfl_xor(a, 8, 64);
        acc[j] = a;
    }
    if (kl == 0) {
        #pragma unroll
        for (int j = 0; j < 8; ++j) {
            const int b = bl * 8 + j;
            ws[((size_t)ky * BB + b) * VV + v] = acc[j];
        }
    }
}

// ---------------- K1b: reduce K-splits + softcap/temperature epilogue ----------------
__global__ __launch_bounds__(512) void reduce_ep(
    const float* __restrict__ ws, const float* __restrict__ temps,
    float* __restrict__ out)
{
    const size_t flat = (size_t)blockIdx.x * 512 + threadIdx.x;   // < 32*VV
    const int b = (int)(flat / VV);
    const int v = (int)(flat - (size_t)b * VV);
    float s = 0.0f;
    #pragma unroll
    for (int ky = 0; ky < KSPLIT; ++ky)
        s += ws[((size_t)ky * BB + b) * VV + v];
    float l = tanhf(s / 30.0f) * 30.0f;    // final logit softcapping
    l = l / temps[b];                       // temperature
    out[32 + (size_t)b * VV + v] = l;
}

// ---------------- Fallback K1 (R12, passed @ ~607us) if ws too small ----------------
__global__ __launch_bounds__(512, 2) void gemv_fb(
    const float* __restrict__ emb, const float* __restrict__ hidden,
    const int* __restrict__ outpos, const float* __restrict__ temps,
    float* __restrict__ out)
{
    __shared__ float h[32][512];
    __shared__ float lout[32][33];

    const int tid   = threadIdx.x;
    const int w     = tid >> 6;
    const int lane  = tid & 63;
    const int kl    = lane & 15;
    const int bl    = lane >> 4;
    const int vbase = blockIdx.x * 32;
    const int pos   = outpos[0];

    const float* hbase = hidden + (size_t)pos * DD;
    const float* er0 = emb + (size_t)(vbase + w * 4 + 0) * DD + (kl << 2);
    const float* er1 = er0 + DD;
    const float* er2 = er1 + DD;
    const float* er3 = er2 + DD;

    int ads[8];
    #pragma unroll
    for (int j = 0; j < 8; ++j) ads[j] = ((bl * 8 + j) * 512 + (kl << 2)) * 4;
    char* hb = (char*)h;

    float acc[4][8];
    #pragma unroll
    for (int v = 0; v < 4; ++v)
        #pragma unroll
        for (int j = 0; j < 8; ++j) acc[v][j] = 0.0f;

    float4 eA0, eA1, eA2, eA3, eB0, eB1, eB2, eB3;

    #define STAGE(P) { \
        _Pragma("unroll") \
        for (int i = 0; i < 8; ++i) { \
            const int x = i * 8 + w; \
            const float* src = hbase + (size_t)(x >> 1) * (SS * DD) \
                             + (P) * 512 + (x & 1) * 256 + (lane << 2); \
            GLDS(src, &h[x >> 1][(x & 1) * 256]); \
        } }
    #define FMAQ(V, E, J) \
        acc[V][J] += E.x * hv.x; acc[V][J] += E.y * hv.y; \
        acc[V][J] += E.z * hv.z; acc[V][J] += E.w * hv.w;
    #define CHUNK(C, C0, C1, C2, C3, N0, N1, N2, N3) { \
        const int np = ((C) < 7) ? p : ((p < 3) ? p + 1 : 3); \
        const int nc = ((C) < 7) ? (C) + 1 : 0; \
        const int no = np * 512 + nc * 64; \
        N0 = *reinterpret_cast<const float4*>(er0 + no); \
        N1 = *reinterpret_cast<const float4*>(er1 + no); \
        N2 = *reinterpret_cast<const float4*>(er2 + no); \
        N3 = *reinterpret_cast<const float4*>(er3 + no); \
        _Pragma("unroll") \
        for (int j = 0; j < 8; ++j) { \
            const float4 hv = *reinterpret_cast<const float4*>(hb + ads[j] + (C) * 256); \
            FMAQ(0, C0, j) FMAQ(1, C1, j) FMAQ(2, C2, j) FMAQ(3, C3, j) \
        } }

    #pragma unroll 1
    for (int p = 0; p < 4; ++p) {
        if (p == 0) {
            STAGE(0)
            CBAR();
            eA0 = *reinterpret_cast<const float4*>(er0);
            eA1 = *reinterpret_cast<const float4*>(er1);
            eA2 = *reinterpret_cast<const float4*>(er2);
            eA3 = *reinterpret_cast<const float4*>(er3);
            CBAR();
            asm volatile("s_waitcnt vmcnt(4)" ::: "memory");
            __builtin_amdgcn_s_barrier();
        } else {
            __builtin_amdgcn_s_barrier();
            CBAR();
            STAGE(p)
            CBAR();
            asm volatile("s_waitcnt vmcnt(0)" ::: "memory");
            __builtin_amdgcn_s_barrier();
        }
        CBAR();
        CHUNK(0, eA0, eA1, eA2, eA3, eB0, eB1, eB2, eB3)
        CHUNK(1, eB0, eB1, eB2, eB3, eA0, eA1, eA2, eA3)
        CHUNK(2, eA0, eA1, eA2, eA3, eB0, eB1, eB2, eB3)
        CHUNK(3, eB0, eB1, eB2, eB3, eA0, eA1, eA2, eA3)
        CHUNK(4, eA0, eA1, eA2, eA3, eB0, eB1, eB2, eB3)
        CHUNK(5, eB0, eB1, eB2, eB3, eA0, eA1, eA2, eA3)
        CHUNK(6, eA0, eA1, eA2, eA3, eB0, eB1, eB2, eB3)
        CHUNK(7, eB0, eB1, eB2, eB3, eA0, eA1, eA2, eA3)
        CBAR();
    }
    #undef CHUNK
    #undef FMAQ
    #undef STAGE

    asm volatile("" :: "v"(eA0.x), "v"(eA1.x), "v"(eA2.x), "v"(eA3.x));

    #pragma unroll
    for (int v = 0; v < 4; ++v)
        #pragma unroll
        for (int j = 0; j < 8; ++j) {
            float a = acc[v][j];
            a += __shfl_xor(a, 1, 64);
            a += __shfl_xor(a, 2, 64);
            a += __shfl_xor(a, 4, 64);
            a += __shfl_xor(a, 8, 64);
            acc[v][j] = a;
        }

    __syncthreads();
    if (kl == 0) {
        #pragma unroll
        for (int v = 0; v < 4; ++v)
            #pragma unroll
            for (int j = 0; j < 8; ++j) {
                float raw = acc[v][j];
                float l = tanhf(raw / 30.0f) * 30.0f;
                l = l / temps[bl * 8 + j];
                lout[w * 4 + v][bl * 8 + j] = l;
            }
    }
    __syncthreads();
    #pragma unroll
    for (int r = 0; r < 2; ++r) {
        const int idx = tid + r * 512;
        const int b2  = idx >> 5;
        const int v2  = idx & 31;
        out[32 + (size_t)b2 * VV + vbase + v2] = lout[v2][b2];
    }
}

// ---------------- K2: per-row top-64 (prob-sorted, stable) + exact-RNG categorical ----------------
__global__ __launch_bounds__(1024) void sample_kernel(
    float* __restrict__ dout, const float* __restrict__ top_ps,
    const int* __restrict__ top_ks)
{
    const int b   = blockIdx.x;
    const int tid = threadIdx.x;
    const float* row = dout + 32 + (size_t)b * VV;

    __shared__ unsigned int hist[2048];
    __shared__ unsigned long long arr[NCAND];
    __shared__ float red[1024];
    __shared__ float m_sh;
    __shared__ unsigned int thresh_sh;
    __shared__ unsigned int cnt_sh;
    __shared__ float p_arr[64];
    __shared__ unsigned int idx_arr[64];
    __shared__ float S_sh;
    __shared__ unsigned long long keep_sh;

    for (int i = tid; i < 2048; i += 1024) hist[i] = 0u;
    for (int i = tid; i < NCAND; i += 1024) arr[i] = 0ull;
    if (tid == 0) cnt_sh = 0u;
    __syncthreads();

    float lmax = -INFINITY;
    for (int i = tid; i < VV; i += 1024) {
        float l = row[i];
        lmax = fmaxf(lmax, l);
        atomicAdd(&hist[enc_f32(l) >> 21], 1u);
    }
    red[tid] = lmax;
    __syncthreads();
    for (int s = 512; s > 0; s >>= 1) {
        if (tid < s) red[tid] = fmaxf(red[tid], red[tid + s]);
        __syncthreads();
    }
    if (tid == 0) {
        float m = red[0];
        m_sh = m;
        int t = (int)(enc_f32(m) >> 21);
        unsigned int cum = 0u;
        for (; t >= 0; --t) { cum += hist[t]; if (cum >= 64u) break; }
        if (t < 0) t = 0;
        thresh_sh = ((unsigned int)t) << 21;
    }
    __syncthreads();
    const float m = m_sh;
    const unsigned int thresh = thresh_sh;

    float z = 0.0f;
    for (int i = tid; i < VV; i += 1024) z += expf(row[i] - m);
    red[tid] = z;
    __syncthreads();
    for (int s = 512; s > 0; s >>= 1) {
        if (tid < s) red[tid] += red[tid + s];
        __syncthreads();
    }
    const float Z = red[0];
    __syncthreads();

    for (int i = tid; i < VV; i += 1024) {
        float l = row[i];
        if (enc_f32(l) >= thresh) {
            float p = expf(l - m) / Z;
            unsigned int slot = atomicAdd(&cnt_sh, 1u);
            if (slot < NCAND)
                arr[slot] = ((unsigned long long)enc_f32(p) << 32)
                          | (unsigned long long)(~(unsigned int)i);
        }
    }
    __syncthreads();

    for (int k = 2; k <= NCAND; k <<= 1) {
        for (int j = k >> 1; j > 0; j >>= 1) {
            for (int t = tid; t < NCAND; t += 1024) {
                int ixj = t ^ j;
                if (ixj > t) {
                    unsigned long long a = arr[t], c = arr[ixj];
                    bool desc = ((t & k) == 0);
                    if (desc ? (a < c) : (a > c)) { arr[t] = c; arr[ixj] = a; }
                }
            }
            __syncthreads();
        }
    }

    if (tid < 64) {
        unsigned long long key = arr[tid];
        p_arr[tid]   = __uint_as_float((unsigned int)(key >> 32) & 0x7FFFFFFFu);
        idx_arr[tid] = ~((unsigned int)(key & 0xFFFFFFFFull));
    }
    __syncthreads();

    if (tid == 0) {
        float cum = 0.0f, S = 0.0f;
        unsigned long long keep = 0ull;
        const float tp = top_ps[b];
        const int   tk = top_ks[b];
        for (int r = 0; r < 64; ++r) {
            float p = p_arr[r];
            cum = cum + p;
            float excl = cum - p;
            if (!(excl > tp) && (r < tk)) { keep |= (1ull << r); S = S + p; }
        }
        S_sh = S; keep_sh = keep;
    }
    __syncthreads();

    if (tid < 64) {
        unsigned long long pk = 0ull;
        if ((keep_sh >> tid) & 1ull) {
            float q  = p_arr[tid] / S_sh;
            float lp = logf(q);
            unsigned int idx = idx_arr[tid];
            float g = gumbel_at((unsigned int)b * (unsigned int)VV + idx);
            float vf = lp + g;
            pk = ((unsigned long long)enc_f32(vf) << 32)
               | (unsigned long long)(~idx);
        }
        for (int off = 1; off < 64; off <<= 1) {
            unsigned long long o = __shfl_xor(pk, off, 64);
            if (o > pk) pk = o;
        }
        if (tid == 0) {
            unsigned int token = ~((unsigned int)(pk & 0xFFFFFFFFull));
            dout[b] = (float)token;
        }
    }
}

extern "C" void kernel_launch(void* const* d_in, const int* in_sizes, int n_in,
                              void* d_out, int out_size, void* d_ws, size_t ws_size,
                              hipStream_t stream) {
    const float* emb   = (const float*)d_in[0];
    const float* hid   = (const float*)d_in[1];
    const int*   pos   = (const int*)d_in[2];
    const float* temps = (const float*)d_in[3];
    const float* tps   = (const float*)d_in[4];
    const int*   tks   = (const int*)d_in[5];
    float* out = (float*)d_out;

    if (ws_size >= WS_NEED) {
        float* ws = (float*)d_ws;
        gemv_part<<<dim3(VV / 8, KSPLIT), dim3(512), 0, stream>>>(emb, hid, pos, ws);
        reduce_ep<<<dim3(BB * VV / 512), dim3(512), 0, stream>>>(ws, temps, out);
    } else {
        gemv_fb<<<dim3(VV / 32), dim3(512), 0, stream>>>(emb, hid, pos, temps, out);
    }
    sample_kernel<<<dim3(BB), dim3(1024), 0, stream>>>(out, tps, tks);
}

// Round 14
// 741.627 us; speedup vs baseline: 1.1824x; 1.1824x over previous
//
#include <hip/hip_runtime.h>
#include <stdint.h>
#include <math.h>

#define VV 128000
#define DD 2048
#define BB 32
#define SS 8
#define NCAND 4096
#define KSPLIT 4
#define KSL 512            // k per split
#define WS_NEED ((size_t)KSPLIT * BB * VV * 4)

// jax_threefry_partitionable 32-bit stream: counter=(0,flat), bits = o0 ^ o1.  (verified R4+)

#define GLDS(src, dst) __builtin_amdgcn_global_load_lds( \
    (const __attribute__((address_space(1))) void*)(src), \
    (__attribute__((address_space(3))) void*)(dst), 16, 0, 0)
#define CBAR() asm volatile("" ::: "memory")

// ---------------- threefry2x32 core (key = (0, 42) from jax.random.key(42)) ----------------
__device__ __forceinline__ uint32_t rotl32(uint32_t x, uint32_t r) {
    return (x << r) | (x >> (32u - r));
}

__device__ __forceinline__ void threefry2x32(uint32_t c0, uint32_t c1,
                                             uint32_t& o0, uint32_t& o1) {
    const uint32_t k0 = 0u, k1 = 42u;
    const uint32_t k2 = 0x1BD11BDAu ^ k0 ^ k1;
    uint32_t x0 = c0 + k0;
    uint32_t x1 = c1 + k1;
    #define TF_ROUND(r) { x0 += x1; x1 = rotl32(x1, r); x1 ^= x0; }
    TF_ROUND(13) TF_ROUND(15) TF_ROUND(26) TF_ROUND(6)
    x0 += k1; x1 += k2 + 1u;
    TF_ROUND(17) TF_ROUND(29) TF_ROUND(16) TF_ROUND(24)
    x0 += k2; x1 += k0 + 2u;
    TF_ROUND(13) TF_ROUND(15) TF_ROUND(26) TF_ROUND(6)
    x0 += k0; x1 += k1 + 3u;
    TF_ROUND(17) TF_ROUND(29) TF_ROUND(16) TF_ROUND(24)
    x0 += k1; x1 += k2 + 4u;
    TF_ROUND(13) TF_ROUND(15) TF_ROUND(26) TF_ROUND(6)
    x0 += k2; x1 += k0 + 5u;
    #undef TF_ROUND
    o0 = x0; o1 = x1;
}

__device__ float gumbel_at(uint32_t flat) {
    uint32_t o0, o1;
    threefry2x32(0u, flat, o0, o1);
    uint32_t bits = o0 ^ o1;
    uint32_t fb = (bits >> 9) | 0x3F800000u;
    float f = __uint_as_float(fb) - 1.0f;
    const float TINY = 1.17549435e-38f;
    float u = (f > 0.0f) ? f : TINY;
    return -logf(-logf(u));
}

__device__ __forceinline__ uint32_t enc_f32(float f) {
    uint32_t u = __float_as_uint(f);
    return u ^ (0x80000000u | (uint32_t)(((int32_t)u) >> 31));
}

// ---------------- K1a: partial GEMV over one K-slice ----------------
// grid (VV/32, KSPLIT) x 512 thr (8 waves). Block: 32 v-rows x 32 b x 512 k.
// Wave w owns v-rows vbase+w*4..+3 -> each emb element read by exactly one
// wave (kl-contiguous 256B segments). Thread: kl=lane&15 (k-split),
// bl=lane>>4 (batch octet); tile 4v x 8b = acc[32]; 1 FMA per LDS byte.
// h[32][512] (64KB) staged ONCE via 8 GLDS/thread + one vmcnt(0)+barrier;
// then the 512-k sweep is straight-line, barrier-free, wait-free (compiler
// software-pipelines the 32 e-loads). 2 blocks/CU x 8 waves = 4 waves/SIMD
// of independent latency cover.
__global__ __launch_bounds__(512, 3) void gemv_part(
    const float* __restrict__ emb, const float* __restrict__ hidden,
    const int* __restrict__ outpos, float* __restrict__ ws)
{
    __shared__ float h[BB][KSL];   // 64 KB exactly

    const int tid  = threadIdx.x;
    const int w    = tid >> 6;
    const int lane = tid & 63;
    const int kl   = lane & 15;
    const int bl   = lane >> 4;
    const int ky   = blockIdx.y;
    const int vbase = blockIdx.x * 32;
    const int pos  = outpos[0];

    const float* hbase = hidden + (size_t)pos * DD + ky * KSL;

    // stage h[32][512]: instr (i,w): x=i*8+w -> row x>>1, half x&1
    #pragma unroll
    for (int i = 0; i < 8; ++i) {
        const int x = i * 8 + w;
        GLDS(hbase + (size_t)(x >> 1) * (SS * DD) + (x & 1) * 256 + (lane << 2),
             &h[x >> 1][(x & 1) * 256]);
    }
    CBAR();
    asm volatile("s_waitcnt vmcnt(0)" ::: "memory");
    __builtin_amdgcn_s_barrier();
    CBAR();

    // e row pointers: wave's 4 rows at this lane's kl slot
    const float* er0 = emb + (size_t)(vbase + w * 4 + 0) * DD + ky * KSL + (kl << 2);
    const float* er1 = er0 + DD;
    const float* er2 = er1 + DD;
    const float* er3 = er2 + DD;

    float acc[4][8];
    #pragma unroll
    for (int v = 0; v < 4; ++v)
        #pragma unroll
        for (int j = 0; j < 8; ++j) acc[v][j] = 0.0f;

    const char* hbb = (const char*)&h[0][0];
    const int adsbase = (bl * 8) * (KSL * 4) + (kl << 4);

    // fully unrolled 8 chunks of 64k: 4 e-loads + 8 ds_read_b128 + 128 FMAs
    #pragma unroll
    for (int c = 0; c < 8; ++c) {
        const int ko = c * 64;
        const float4 e0 = *reinterpret_cast<const float4*>(er0 + ko);
        const float4 e1 = *reinterpret_cast<const float4*>(er1 + ko);
        const float4 e2 = *reinterpret_cast<const float4*>(er2 + ko);
        const float4 e3 = *reinterpret_cast<const float4*>(er3 + ko);
        #pragma unroll
        for (int j = 0; j < 8; ++j) {
            const float4 hv = *reinterpret_cast<const float4*>(
                hbb + adsbase + j * (KSL * 4) + c * 256);
            acc[0][j] += e0.x * hv.x; acc[0][j] += e0.y * hv.y;
            acc[0][j] += e0.z * hv.z; acc[0][j] += e0.w * hv.w;
            acc[1][j] += e1.x * hv.x; acc[1][j] += e1.y * hv.y;
            acc[1][j] += e1.z * hv.z; acc[1][j] += e1.w * hv.w;
            acc[2][j] += e2.x * hv.x; acc[2][j] += e2.y * hv.y;
            acc[2][j] += e2.z * hv.z; acc[2][j] += e2.w * hv.w;
            acc[3][j] += e3.x * hv.x; acc[3][j] += e3.y * hv.y;
            acc[3][j] += e3.z * hv.z; acc[3][j] += e3.w * hv.w;
        }
    }

    // reduce over the 16 kl lanes
    #pragma unroll
    for (int v = 0; v < 4; ++v)
        #pragma unroll
        for (int j = 0; j < 8; ++j) {
            float a = acc[v][j];
            a += __shfl_xor(a, 1, 64);
            a += __shfl_xor(a, 2, 64);
            a += __shfl_xor(a, 4, 64);
            a += __shfl_xor(a, 8, 64);
            acc[v][j] = a;
        }
    if (kl == 0) {
        #pragma unroll
        for (int v = 0; v < 4; ++v)
            #pragma unroll
            for (int j = 0; j < 8; ++j) {
                const int b = bl * 8 + j;
                ws[((size_t)ky * BB + b) * VV + (vbase + w * 4 + v)] = acc[v][j];
            }
    }
}

// ---------------- K1b: reduce K-splits + softcap/temperature epilogue ----------------
__global__ __launch_bounds__(512) void reduce_ep(
    const float* __restrict__ ws, const float* __restrict__ temps,
    float* __restrict__ out)
{
    const size_t flat = (size_t)blockIdx.x * 512 + threadIdx.x;   // < 32*VV
    const int b = (int)(flat / VV);
    const int v = (int)(flat - (size_t)b * VV);
    float s = 0.0f;
    #pragma unroll
    for (int ky = 0; ky < KSPLIT; ++ky)
        s += ws[((size_t)ky * BB + b) * VV + v];
    float l = tanhf(s / 30.0f) * 30.0f;    // final logit softcapping
    l = l / temps[b];                       // temperature
    out[32 + (size_t)b * VV + v] = l;
}

// ---------------- Fallback K1 (R12, passed) if ws too small ----------------
__global__ __launch_bounds__(512, 2) void gemv_fb(
    const float* __restrict__ emb, const float* __restrict__ hidden,
    const int* __restrict__ outpos, const float* __restrict__ temps,
    float* __restrict__ out)
{
    __shared__ float h[32][512];
    __shared__ float lout[32][33];

    const int tid   = threadIdx.x;
    const int w     = tid >> 6;
    const int lane  = tid & 63;
    const int kl    = lane & 15;
    const int bl    = lane >> 4;
    const int vbase = blockIdx.x * 32;
    const int pos   = outpos[0];

    const float* hbase = hidden + (size_t)pos * DD;
    const float* er0 = emb + (size_t)(vbase + w * 4 + 0) * DD + (kl << 2);
    const float* er1 = er0 + DD;
    const float* er2 = er1 + DD;
    const float* er3 = er2 + DD;

    int ads[8];
    #pragma unroll
    for (int j = 0; j < 8; ++j) ads[j] = ((bl * 8 + j) * 512 + (kl << 2)) * 4;
    char* hb = (char*)h;

    float acc[4][8];
    #pragma unroll
    for (int v = 0; v < 4; ++v)
        #pragma unroll
        for (int j = 0; j < 8; ++j) acc[v][j] = 0.0f;

    float4 eA0, eA1, eA2, eA3, eB0, eB1, eB2, eB3;

    #define STAGE(P) { \
        _Pragma("unroll") \
        for (int i = 0; i < 8; ++i) { \
            const int x = i * 8 + w; \
            const float* src = hbase + (size_t)(x >> 1) * (SS * DD) \
                             + (P) * 512 + (x & 1) * 256 + (lane << 2); \
            GLDS(src, &h[x >> 1][(x & 1) * 256]); \
        } }
    #define FMAQ(V, E, J) \
        acc[V][J] += E.x * hv.x; acc[V][J] += E.y * hv.y; \
        acc[V][J] += E.z * hv.z; acc[V][J] += E.w * hv.w;
    #define CHUNK(C, C0, C1, C2, C3, N0, N1, N2, N3) { \
        const int np = ((C) < 7) ? p : ((p < 3) ? p + 1 : 3); \
        const int nc = ((C) < 7) ? (C) + 1 : 0; \
        const int no = np * 512 + nc * 64; \
        N0 = *reinterpret_cast<const float4*>(er0 + no); \
        N1 = *reinterpret_cast<const float4*>(er1 + no); \
        N2 = *reinterpret_cast<const float4*>(er2 + no); \
        N3 = *reinterpret_cast<const float4*>(er3 + no); \
        _Pragma("unroll") \
        for (int j = 0; j < 8; ++j) { \
            const float4 hv = *reinterpret_cast<const float4*>(hb + ads[j] + (C) * 256); \
            FMAQ(0, C0, j) FMAQ(1, C1, j) FMAQ(2, C2, j) FMAQ(3, C3, j) \
        } }

    #pragma unroll 1
    for (int p = 0; p < 4; ++p) {
        if (p == 0) {
            STAGE(0)
            CBAR();
            eA0 = *reinterpret_cast<const float4*>(er0);
            eA1 = *reinterpret_cast<const float4*>(er1);
            eA2 = *reinterpret_cast<const float4*>(er2);
            eA3 = *reinterpret_cast<const float4*>(er3);
            CBAR();
            asm volatile("s_waitcnt vmcnt(4)" ::: "memory");
            __builtin_amdgcn_s_barrier();
        } else {
            __builtin_amdgcn_s_barrier();
            CBAR();
            STAGE(p)
            CBAR();
            asm volatile("s_waitcnt vmcnt(0)" ::: "memory");
            __builtin_amdgcn_s_barrier();
        }
        CBAR();
        CHUNK(0, eA0, eA1, eA2, eA3, eB0, eB1, eB2, eB3)
        CHUNK(1, eB0, eB1, eB2, eB3, eA0, eA1, eA2, eA3)
        CHUNK(2, eA0, eA1, eA2, eA3, eB0, eB1, eB2, eB3)
        CHUNK(3, eB0, eB1, eB2, eB3, eA0, eA1, eA2, eA3)
        CHUNK(4, eA0, eA1, eA2, eA3, eB0, eB1, eB2, eB3)
        CHUNK(5, eB0, eB1, eB2, eB3, eA0, eA1, eA2, eA3)
        CHUNK(6, eA0, eA1, eA2, eA3, eB0, eB1, eB2, eB3)
        CHUNK(7, eB0, eB1, eB2, eB3, eA0, eA1, eA2, eA3)
        CBAR();
    }
    #undef CHUNK
    #undef FMAQ
    #undef STAGE

    asm volatile("" :: "v"(eA0.x), "v"(eA1.x), "v"(eA2.x), "v"(eA3.x));

    #pragma unroll
    for (int v = 0; v < 4; ++v)
        #pragma unroll
        for (int j = 0; j < 8; ++j) {
            float a = acc[v][j];
            a += __shfl_xor(a, 1, 64);
            a += __shfl_xor(a, 2, 64);
            a += __shfl_xor(a, 4, 64);
            a += __shfl_xor(a, 8, 64);
            acc[v][j] = a;
        }

    __syncthreads();
    if (kl == 0) {
        #pragma unroll
        for (int v = 0; v < 4; ++v)
            #pragma unroll
            for (int j = 0; j < 8; ++j) {
                float raw = acc[v][j];
                float l = tanhf(raw / 30.0f) * 30.0f;
                l = l / temps[bl * 8 + j];
                lout[w * 4 + v][bl * 8 + j] = l;
            }
    }
    __syncthreads();
    #pragma unroll
    for (int r = 0; r < 2; ++r) {
        const int idx = tid + r * 512;
        const int b2  = idx >> 5;
        const int v2  = idx & 31;
        out[32 + (size_t)b2 * VV + vbase + v2] = lout[v2][b2];
    }
}

// ---------------- K2: per-row top-64 (prob-sorted, stable) + exact-RNG categorical ----------------
__global__ __launch_bounds__(1024) void sample_kernel(
    float* __restrict__ dout, const float* __restrict__ top_ps,
    const int* __restrict__ top_ks)
{
    const int b   = blockIdx.x;
    const int tid = threadIdx.x;
    const float* row = dout + 32 + (size_t)b * VV;

    __shared__ unsigned int hist[2048];
    __shared__ unsigned long long arr[NCAND];
    __shared__ float red[1024];
    __shared__ float m_sh;
    __shared__ unsigned int thresh_sh;
    __shared__ unsigned int cnt_sh;
    __shared__ float p_arr[64];
    __shared__ unsigned int idx_arr[64];
    __shared__ float S_sh;
    __shared__ unsigned long long keep_sh;

    for (int i = tid; i < 2048; i += 1024) hist[i] = 0u;
    for (int i = tid; i < NCAND; i += 1024) arr[i] = 0ull;
    if (tid == 0) cnt_sh = 0u;
    __syncthreads();

    float lmax = -INFINITY;
    for (int i = tid; i < VV; i += 1024) {
        float l = row[i];
        lmax = fmaxf(lmax, l);
        atomicAdd(&hist[enc_f32(l) >> 21], 1u);
    }
    red[tid] = lmax;
    __syncthreads();
    for (int s = 512; s > 0; s >>= 1) {
        if (tid < s) red[tid] = fmaxf(red[tid], red[tid + s]);
        __syncthreads();
    }
    if (tid == 0) {
        float m = red[0];
        m_sh = m;
        int t = (int)(enc_f32(m) >> 21);
        unsigned int cum = 0u;
        for (; t >= 0; --t) { cum += hist[t]; if (cum >= 64u) break; }
        if (t < 0) t = 0;
        thresh_sh = ((unsigned int)t) << 21;
    }
    __syncthreads();
    const float m = m_sh;
    const unsigned int thresh = thresh_sh;

    float z = 0.0f;
    for (int i = tid; i < VV; i += 1024) z += expf(row[i] - m);
    red[tid] = z;
    __syncthreads();
    for (int s = 512; s > 0; s >>= 1) {
        if (tid < s) red[tid] += red[tid + s];
        __syncthreads();
    }
    const float Z = red[0];
    __syncthreads();

    for (int i = tid; i < VV; i += 1024) {
        float l = row[i];
        if (enc_f32(l) >= thresh) {
            float p = expf(l - m) / Z;
            unsigned int slot = atomicAdd(&cnt_sh, 1u);
            if (slot < NCAND)
                arr[slot] = ((unsigned long long)enc_f32(p) << 32)
                          | (unsigned long long)(~(unsigned int)i);
        }
    }
    __syncthreads();

    for (int k = 2; k <= NCAND; k <<= 1) {
        for (int j = k >> 1; j > 0; j >>= 1) {
            for (int t = tid; t < NCAND; t += 1024) {
                int ixj = t ^ j;
                if (ixj > t) {
                    unsigned long long a = arr[t], c = arr[ixj];
                    bool desc = ((t & k) == 0);
                    if (desc ? (a < c) : (a > c)) { arr[t] = c; arr[ixj] = a; }
                }
            }
            __syncthreads();
        }
    }

    if (tid < 64) {
        unsigned long long key = arr[tid];
        p_arr[tid]   = __uint_as_float((unsigned int)(key >> 32) & 0x7FFFFFFFu);
        idx_arr[tid] = ~((unsigned int)(key & 0xFFFFFFFFull));
    }
    __syncthreads();

    if (tid == 0) {
        float cum = 0.0f, S = 0.0f;
        unsigned long long keep = 0ull;
        const float tp = top_ps[b];
        const int   tk = top_ks[b];
        for (int r = 0; r < 64; ++r) {
            float p = p_arr[r];
            cum = cum + p;
            float excl = cum - p;
            if (!(excl > tp) && (r < tk)) { keep |= (1ull << r); S = S + p; }
        }
        S_sh = S; keep_sh = keep;
    }
    __syncthreads();

    if (tid < 64) {
        unsigned long long pk = 0ull;
        if ((keep_sh >> tid) & 1ull) {
            float q  = p_arr[tid] / S_sh;
            float lp = logf(q);
            unsigned int idx = idx_arr[tid];
            float g = gumbel_at((unsigned int)b * (unsigned int)VV + idx);
            float vf = lp + g;
            pk = ((unsigned long long)enc_f32(vf) << 32)
               | (unsigned long long)(~idx);
        }
        for (int off = 1; off < 64; off <<= 1) {
            unsigned long long o = __shfl_xor(pk, off, 64);
            if (o > pk) pk = o;
        }
        if (tid == 0) {
            unsigned int token = ~((unsigned int)(pk & 0xFFFFFFFFull));
            dout[b] = (float)token;
        }
    }
}

extern "C" void kernel_launch(void* const* d_in, const int* in_sizes, int n_in,
                              void* d_out, int out_size, void* d_ws, size_t ws_size,
                              hipStream_t stream) {
    const float* emb   = (const float*)d_in[0];
    const float* hid   = (const float*)d_in[1];
    const int*   pos   = (const int*)d_in[2];
    const float* temps = (const float*)d_in[3];
    const float* tps   = (const float*)d_in[4];
    const int*   tks   = (const int*)d_in[5];
    float* out = (float*)d_out;

    if (ws_size >= WS_NEED) {
        float* ws = (float*)d_ws;
        gemv_part<<<dim3(VV / 32, KSPLIT), dim3(512), 0, stream>>>(emb, hid, pos, ws);
        reduce_ep<<<dim3(BB * VV / 512), dim3(512), 0, stream>>>(ws, temps, out);
    } else {
        gemv_fb<<<dim3(VV / 32), dim3(512), 0, stream>>>(emb, hid, pos, temps, out);
    }
    sample_kernel<<<dim3(BB), dim3(1024), 0, stream>>>(out, tps, tks);
}